// Round 1
// baseline (3522.318 us; speedup 1.0000x reference)
//
#include <hip/hip_runtime.h>
#include <math.h>

#define NC 60
#define ND 952
#define DE 2040
#define NG 17737
#define NF 881
#define GAMMA_C 8.7f
#define EPS_BN 1e-5f

// ---- workspace layout (float offsets) ----
#define O_DX      0          // 60
#define O_DC      60         // 60
#define O_DY      120        // 952
#define O_DDV     1072       // 952
#define O_B4H     2024       // 60
#define O_A4H     2084       // 952
#define O_CMU     3036       // 60
#define O_CIS     3096       // 60
#define O_DMU     3156       // 952
#define O_DIS     4108       // 952
#define O_ADJT    5120       // 952*60 = 57120
#define O_CF      62240      // 60*17737 = 1064220
#define O_EMBC    1126460    // 60*2040
#define O_EMBD    1248860    // 952*2040
#define O_CSUM    3190940    // 60*2040
#define O_DSUM    3313340    // 952*2040
#define O_XC      5255420    // 60*8160
#define O_XD      5745020    // 952*8160  (end 13513340 floats = 54.1 MB)
#define MEMSET_FLOATS 4128960  // embC..dsum contiguous zero-init (atomic targets)

struct BZ { long long off[16]; };

__device__ __forceinline__ float blockReduceSum(float v, float* red) {
    const int t = threadIdx.x;
    red[t] = v;
    __syncthreads();
    for (int off = 128; off > 0; off >>= 1) {
        if (t < off) red[t] += red[t + off];
        __syncthreads();
    }
    float r = red[0];
    __syncthreads();
    return r;
}

// ---- scalars: rs/cs/dx/dy/dc/dd, b4h, a4h, adj^T ----
__global__ __launch_bounds__(256) void k_pre(
    const float* __restrict__ adj, const float* __restrict__ ch,
    const float* __restrict__ dh, float* __restrict__ ws)
{
    __shared__ float red[256];
    const int b = blockIdx.x, t = threadIdx.x;
    if (b < NC) {
        const int c = b;
        float s = 0.f;
        for (int j = t; j < ND; j += 256) s += adj[c * ND + j];
        float rs = blockReduceSum(s, red) + 1.f;
        if (t == 0) { ws[O_DX + c] = rsqrtf(rs); ws[O_DC + c] = 1.f / rs + 1.f; }
        float s2 = (t < NC) ? ch[c * NC + t] : 0.f;
        float hs = blockReduceSum(s2, red) + 1.f;
        if (t == 0) ws[O_B4H + c] = 1.f / hs;
    } else if (b < NC + ND) {
        const int i = b - NC;
        float s = 0.f;
        for (int j = t; j < ND; j += 256) s += dh[(long long)i * ND + j];
        float hs = blockReduceSum(s, red) + 1.f;
        if (t == 0) ws[O_A4H + i] = 1.f / hs;
        float s2 = (t < NC) ? adj[t * ND + i] : 0.f;
        float cs = blockReduceSum(s2, red) + 1.f;
        if (t == 0) { ws[O_DY + i] = rsqrtf(cs); ws[O_DDV + i] = 1.f / cs + 1.f; }
    } else {
        const int idx = (b - NC - ND) * 256 + t;
        if (idx < ND * NC) {
            const int i = idx / NC, c = idx % NC;
            ws[O_ADJT + idx] = adj[c * ND + i];
        }
    }
}

// ---- per-row z-norm of cell_exprs (ddof=1) ----
__global__ __launch_bounds__(256) void k_znorm(
    const float* __restrict__ x, float* __restrict__ out)
{
    __shared__ float r1[256];
    __shared__ float r2[256];
    const int c = blockIdx.x, t = threadIdx.x;
    const float* row = x + (long long)c * NG;
    float s = 0.f, q = 0.f;
    for (int j = t; j < NG; j += 256) { float v = row[j]; s += v; q += v * v; }
    r1[t] = s; r2[t] = q;
    __syncthreads();
    for (int off = 128; off > 0; off >>= 1) {
        if (t < off) { r1[t] += r1[t + off]; r2[t] += r2[t + off]; }
        __syncthreads();
    }
    const float mu = r1[0] / (float)NG;
    const float var = (r2[0] - (float)NG * mu * mu) / (float)(NG - 1);
    const float inv = rsqrtf(var);
    float* orow = out + (long long)c * NG;
    for (int j = t; j < NG; j += 256) orow[j] = (row[j] - mu) * inv;
}

// ---- generic fp32 NT GEMM tile, K-split over blockIdx.z, atomicAdd epilogue ----
// C[m,n] += sum_k A[m,k]*B'[n,k], B' = B + bz.off[z] (per-K-window B base shift)
template<int BM, int BN, int TM, int TN, int KT>
__global__ __launch_bounds__(256) void k_gemm(
    const float* __restrict__ A, int lda,
    const float* __restrict__ B, int ldb,
    float* __restrict__ C, int ldc,
    int M, int N, int K, int kchunk, BZ bz)
{
    __shared__ float As[BM][KT + 2];
    __shared__ float Bs[BN][KT + 2];
    const int t = threadIdx.x;
    const int tr = t >> 4;
    const int tc = t & 15;
    const int m0 = blockIdx.y * BM;
    const int n0 = blockIdx.x * BN;
    const int z = blockIdx.z;
    const int k0 = z * kchunk;
    const int k1 = min(K, k0 + kchunk);
    const float* Bz = B + bz.off[z];

    float acc[TM][TN];
#pragma unroll
    for (int i = 0; i < TM; ++i) {
#pragma unroll
        for (int j = 0; j < TN; ++j) acc[i][j] = 0.f;
    }

    for (int kb = k0; kb < k1; kb += KT) {
#pragma unroll
        for (int q = 0; q < (BM * KT) / 256; ++q) {
            int s = q * 256 + t;
            int row = s / KT, kk = s % KT;
            int m = m0 + row, k = kb + kk;
            float v = 0.f;
            if (m < M && k < k1) v = A[(long long)m * lda + k];
            As[row][kk] = v;
        }
#pragma unroll
        for (int q = 0; q < (BN * KT) / 256; ++q) {
            int s = q * 256 + t;
            int row = s / KT, kk = s % KT;
            int n = n0 + row, k = kb + kk;
            float v = 0.f;
            if (n < N && k < k1) v = Bz[(long long)n * ldb + k];
            Bs[row][kk] = v;
        }
        __syncthreads();
#pragma unroll
        for (int kt = 0; kt < KT; ++kt) {
            float a[TM], bb[TN];
#pragma unroll
            for (int i = 0; i < TM; ++i) a[i] = As[tr + i * 16][kt];
#pragma unroll
            for (int j = 0; j < TN; ++j) bb[j] = Bs[tc + j * 16][kt];
#pragma unroll
            for (int i = 0; i < TM; ++i) {
#pragma unroll
                for (int j = 0; j < TN; ++j) acc[i][j] += a[i] * bb[j];
            }
        }
        __syncthreads();
    }
#pragma unroll
    for (int i = 0; i < TM; ++i) {
        int m = m0 + tr + i * 16;
        if (m >= M) continue;
#pragma unroll
        for (int j = 0; j < TN; ++j) {
            int n = n0 + tc + j * 16;
            if (n < N) atomicAdd(&C[(long long)m * ldc + n], acc[i][j]);
        }
    }
}

// ---- BatchNorm over rows (training stats, biased var), in-place ----
__global__ __launch_bounds__(256) void k_bncols(
    float* __restrict__ X, int R,
    const float* __restrict__ g, const float* __restrict__ bta)
{
    const int d = blockIdx.x * 256 + threadIdx.x;
    if (d >= DE) return;
    float s = 0.f, q = 0.f;
    for (int r = 0; r < R; ++r) { float v = X[(long long)r * DE + d]; s += v; q += v * v; }
    const float mu = s / (float)R;
    float var = q / (float)R - mu * mu;
    var = fmaxf(var, 0.f);
    const float sc = rsqrtf(var + EPS_BN) * g[d];
    const float sh = bta[d] - mu * sc;
    for (int r = 0; r < R; ++r) {
        const long long ix = (long long)r * DE + d;
        X[ix] = X[ix] * sc + sh;
    }
}

// ---- X0 = dc .* exp -> Xc[:,0:D); X2 = dd .* fig -> Xd[:,0:D) ----
__global__ __launch_bounds__(256) void k_scalerows(
    const float* __restrict__ embC, const float* __restrict__ embD,
    const float* __restrict__ dc, const float* __restrict__ dd,
    float* __restrict__ Xc, float* __restrict__ Xd)
{
    const long long idx = (long long)blockIdx.x * 256 + threadIdx.x;
    const long long nc = (long long)NC * DE;
    const long long ndd = (long long)ND * DE;
    if (idx < nc) {
        const int c = (int)(idx / DE), d = (int)(idx % DE);
        Xc[(long long)c * (4 * DE) + d] = dc[c] * embC[idx];
    } else if (idx < nc + ndd) {
        const long long k = idx - nc;
        const int i = (int)(k / DE), d = (int)(k % DE);
        Xd[(long long)i * (4 * DE) + d] = dd[i] * embD[k];
    }
}

// ---- out[m,n] = rsc[m] * sum_k A[m,k]*ksc[k]*B[k,n]   (NN-B, small K) ----
template<int TMv, int KT>
__global__ __launch_bounds__(256) void k_gemm_nns(
    const float* __restrict__ A, int lda,
    const float* __restrict__ rsc, const float* __restrict__ ksc,
    const float* __restrict__ B, int ldb,
    float* __restrict__ C, int ldc,
    int M, int K, int N)
{
    __shared__ float As[TMv][KT];
    const int t = threadIdx.x;
    const int n = blockIdx.x * 256 + t;
    const int m0 = blockIdx.y * TMv;
    float acc[TMv];
#pragma unroll
    for (int i = 0; i < TMv; ++i) acc[i] = 0.f;
    for (int kb = 0; kb < K; kb += KT) {
        if (t < TMv * KT) {
            const int row = t / KT, kk = t % KT;
            const int m = m0 + row, k = kb + kk;
            float v = 0.f;
            if (m < M && k < K) v = A[(long long)m * lda + k] * ksc[k];
            As[row][kk] = v;
        }
        __syncthreads();
        const int kmax = min(KT, K - kb);
        for (int kt = 0; kt < kmax; ++kt) {
            const float bv = (n < N) ? B[(long long)(kb + kt) * ldb + n] : 0.f;
#pragma unroll
            for (int i = 0; i < TMv; ++i) acc[i] += As[i][kt] * bv;
        }
        __syncthreads();
    }
    if (n < N) {
#pragma unroll
        for (int i = 0; i < TMv; ++i) {
            const int m = m0 + i;
            if (m < M) C[(long long)m * ldc + n] = rsc[m] * acc[i];
        }
    }
}

// ---- dual NN GEMM: Ca = H@B ; Cb = B - sv[m]*(H@(sv.*B))  (square H, M==K) ----
template<int BM, int BN, int TM, int TN, int KT>
__global__ __launch_bounds__(256) void k_dualnn(
    const float* __restrict__ A, int lda,
    const float* __restrict__ sv,
    const float* __restrict__ B, int ldb,
    float* __restrict__ Ca, float* __restrict__ Cb, int ldc,
    int M, int K, int N)
{
    __shared__ float As[BM][KT + 2];
    __shared__ float Bs[KT][BN + 1];
    __shared__ float B2[KT][BN + 1];
    const int t = threadIdx.x;
    const int tr = t >> 4;
    const int tc = t & 15;
    const int m0 = blockIdx.y * BM;
    const int n0 = blockIdx.x * BN;
    float acc1[TM][TN], acc2[TM][TN];
#pragma unroll
    for (int i = 0; i < TM; ++i) {
#pragma unroll
        for (int j = 0; j < TN; ++j) { acc1[i][j] = 0.f; acc2[i][j] = 0.f; }
    }
    for (int kb = 0; kb < K; kb += KT) {
#pragma unroll
        for (int q = 0; q < (BM * KT) / 256; ++q) {
            int s = q * 256 + t;
            int row = s / KT, kk = s % KT;
            int m = m0 + row, k = kb + kk;
            As[row][kk] = (m < M && k < K) ? A[(long long)m * lda + k] : 0.f;
        }
#pragma unroll
        for (int q = 0; q < (KT * BN) / 256; ++q) {
            int s = q * 256 + t;
            int kt = s / BN, nn = s % BN;
            int k = kb + kt, n = n0 + nn;
            float v = (k < K && n < N) ? B[(long long)k * ldb + n] : 0.f;
            float sc = (k < K) ? sv[k] : 0.f;
            Bs[kt][nn] = v;
            B2[kt][nn] = v * sc;
        }
        __syncthreads();
#pragma unroll
        for (int kt = 0; kt < KT; ++kt) {
            float a[TM], bb[TN], b2[TN];
#pragma unroll
            for (int i = 0; i < TM; ++i) a[i] = As[tr + i * 16][kt];
#pragma unroll
            for (int j = 0; j < TN; ++j) { bb[j] = Bs[kt][tc + j * 16]; b2[j] = B2[kt][tc + j * 16]; }
#pragma unroll
            for (int i = 0; i < TM; ++i) {
#pragma unroll
                for (int j = 0; j < TN; ++j) {
                    acc1[i][j] += a[i] * bb[j];
                    acc2[i][j] += a[i] * b2[j];
                }
            }
        }
        __syncthreads();
    }
#pragma unroll
    for (int i = 0; i < TM; ++i) {
        const int m = m0 + tr + i * 16;
        if (m >= M) continue;
#pragma unroll
        for (int j = 0; j < TN; ++j) {
            const int n = n0 + tc + j * 16;
            if (n < N) {
                Ca[(long long)m * ldc + n] = acc1[i][j];
                Cb[(long long)m * ldc + n] = B[(long long)m * ldb + n] - sv[m] * acc2[i][j];
            }
        }
    }
}

// ---- epilogue: agg = relu((sum + bias)*(emb+1)) in-place ----
__global__ __launch_bounds__(256) void k_epi(
    float* __restrict__ csum, float* __restrict__ dsum,
    const float* __restrict__ embC, const float* __restrict__ embD,
    const float* __restrict__ b_agg)
{
    const long long idx = (long long)blockIdx.x * 256 + threadIdx.x;
    const long long nc = (long long)NC * DE;
    const long long ndd = (long long)ND * DE;
    if (idx < nc) {
        const int d = (int)(idx % DE);
        const float bc = b_agg[0 * DE + d] + b_agg[1 * DE + d] + b_agg[4 * DE + d] + b_agg[6 * DE + d];
        const float v = (csum[idx] + bc) * (embC[idx] + 1.f);
        csum[idx] = fmaxf(v, 0.f);
    } else if (idx < nc + ndd) {
        const long long k = idx - nc;
        const int d = (int)(k % DE);
        const float bd = b_agg[2 * DE + d] + b_agg[3 * DE + d] + b_agg[5 * DE + d] + b_agg[7 * DE + d];
        const float v = (dsum[k] + bd) * (embD[k] + 1.f);
        dsum[k] = fmaxf(v, 0.f);
    }
}

// ---- per-row mean + 1/||x-mu|| for corr ----
__global__ __launch_bounds__(256) void k_rowstats(
    const float* __restrict__ cagg, const float* __restrict__ dagg,
    float* __restrict__ ws)
{
    __shared__ float red[256];
    const int b = blockIdx.x, t = threadIdx.x;
    const float* row;
    int omu, ois;
    if (b < NC) { row = cagg + (long long)b * DE; omu = O_CMU + b; ois = O_CIS + b; }
    else { const int i = b - NC; row = dagg + (long long)i * DE; omu = O_DMU + i; ois = O_DIS + i; }
    float s = 0.f;
    for (int j = t; j < DE; j += 256) s += row[j];
    const float mu = blockReduceSum(s, red) / (float)DE;
    float q = 0.f;
    for (int j = t; j < DE; j += 256) { const float v = row[j] - mu; q += v * v; }
    const float ss = blockReduceSum(q, red);
    if (t == 0) { ws[omu] = mu; ws[ois] = rsqrtf(ss); }
}

// ---- corr + sigmoid: out[c,i] = sigmoid(g * (x.y - D*mx*my) * cis[c]*dis[i]) ----
__global__ __launch_bounds__(256) void k_corr(
    const float* __restrict__ cagg, const float* __restrict__ dagg,
    const float* __restrict__ ws, float* __restrict__ out)
{
    const int KT = 32;
    __shared__ float xs[16][KT + 1];
    __shared__ float ys[16][KT + 1];
    const int t = threadIdx.x;
    const int tcr = t >> 4, ti = t & 15;
    const int c0 = blockIdx.y * 16, i0 = blockIdx.x * 16;
    float acc = 0.f;
    for (int kb = 0; kb < DE; kb += KT) {
#pragma unroll
        for (int q = 0; q < 2; ++q) {
            const int s = q * 256 + t;
            const int row = s >> 5, kk = s & 31;
            const int k = kb + kk;
            const int c = c0 + row;
            xs[row][kk] = (c < NC && k < DE) ? cagg[(long long)c * DE + k] : 0.f;
            const int i = i0 + row;
            ys[row][kk] = (i < ND && k < DE) ? dagg[(long long)i * DE + k] : 0.f;
        }
        __syncthreads();
#pragma unroll
        for (int kt = 0; kt < KT; ++kt) acc += xs[tcr][kt] * ys[ti][kt];
        __syncthreads();
    }
    const int c = c0 + tcr, i = i0 + ti;
    if (c < NC && i < ND) {
        const float num = acc - (float)DE * ws[O_CMU + c] * ws[O_DMU + i];
        const float corr = num * ws[O_CIS + c] * ws[O_DIS + i];
        out[(long long)c * ND + i] = 1.f / (1.f + expf(-GAMMA_C * corr));
    }
}

extern "C" void kernel_launch(void* const* d_in, const int* in_sizes, int n_in,
                              void* d_out, int out_size, void* d_ws, size_t ws_size,
                              hipStream_t stream)
{
    const float* adj         = (const float*)d_in[0];
    const float* cell_exprs  = (const float*)d_in[1];
    const float* drug_finger = (const float*)d_in[2];
    const float* cell_hyper  = (const float*)d_in[3];
    const float* drug_hyper  = (const float*)d_in[4];
    const float* W_agg       = (const float*)d_in[5];
    const float* b_agg       = (const float*)d_in[6];
    const float* ldd_w       = (const float*)d_in[7];
    const float* lcc_w       = (const float*)d_in[9];
    const float* bnd_g       = (const float*)d_in[11];
    const float* bnd_b       = (const float*)d_in[12];
    const float* bnc_g       = (const float*)d_in[13];
    const float* bnc_b       = (const float*)d_in[14];
    float* ws  = (float*)d_ws;
    float* out = (float*)d_out;

    float* cf   = ws + O_CF;
    float* embC = ws + O_EMBC;
    float* embD = ws + O_EMBD;
    float* csum = ws + O_CSUM;
    float* dsum = ws + O_DSUM;
    float* Xc   = ws + O_XC;
    float* Xd   = ws + O_XD;

    // 1) scalars + adj^T
    k_pre<<<1236, 256, 0, stream>>>(adj, cell_hyper, drug_hyper, ws);
    // 2) row z-norm
    k_znorm<<<NC, 256, 0, stream>>>(cell_exprs, cf);
    // 3) zero atomic-GEMM targets (embC|embD|csum|dsum contiguous)
    hipMemsetAsync((void*)embC, 0, (size_t)MEMSET_FLOATS * sizeof(float), stream);

    BZ bz0;
    for (int z = 0; z < 16; ++z) bz0.off[z] = 0;

    // 4) exp_pre = cf @ lcc_w^T   (K=17737, ksplit=16)
    k_gemm<64, 128, 4, 8, 16><<<dim3(16, 1, 16), 256, 0, stream>>>(
        cf, NG, lcc_w, NG, embC, DE, NC, DE, NG, 1109, bz0);
    // 5) BN cell
    k_bncols<<<8, 256, 0, stream>>>(embC, NC, bnc_g, bnc_b);
    // 6) fig_pre = drug_finger @ ldd_w^T  (K=881, ksplit=2)
    k_gemm<128, 128, 8, 8, 16><<<dim3(16, 8, 2), 256, 0, stream>>>(
        drug_finger, NF, ldd_w, NF, embD, DE, ND, DE, NF, 441, bz0);
    // 7) BN drug
    k_bncols<<<8, 256, 0, stream>>>(embD, ND, bnd_g, bnd_b);
    // 8) X0, X2 (diag row scalings)
    k_scalerows<<<8065, 256, 0, stream>>>(embC, embD, ws + O_DC, ws + O_DDV, Xc, Xd);
    // 9) X1 = dx .* (adj @ (dy .* fig))
    k_gemm_nns<8, 16><<<dim3(8, 8), 256, 0, stream>>>(
        adj, ND, ws + O_DX, ws + O_DY, embD, DE, Xc + DE, 4 * DE, NC, ND, DE);
    // 10) X3 = dy .* (adjT @ (dx .* exp))
    k_gemm_nns<8, 16><<<dim3(8, 119), 256, 0, stream>>>(
        ws + O_ADJT, NC, ws + O_DY, ws + O_DX, embC, DE, Xd + DE, 4 * DE, ND, NC, DE);
    // 11) X4 = CH@exp ; X6 = exp - b4h.*(CH@(b4h.*exp))
    k_dualnn<64, 64, 4, 4, 16><<<dim3(32, 1), 256, 0, stream>>>(
        cell_hyper, NC, ws + O_B4H, embC, DE, Xc + 2 * DE, Xc + 3 * DE, 4 * DE, NC, NC, DE);
    // 12) X5 = DH@fig ; X7 = fig - a4h.*(DH@(a4h.*fig))
    k_dualnn<64, 64, 4, 4, 16><<<dim3(32, 15), 256, 0, stream>>>(
        drug_hyper, ND, ws + O_A4H, embD, DE, Xd + 2 * DE, Xd + 3 * DE, 4 * DE, ND, ND, DE);

    // 13) cell main GEMM: csum = Xc @ [W0|W1|W4|W6]^T  (K=8160 as 16 windows of 510)
    BZ bzc;
    {
        const int permc[4] = {0, 1, 4, 6};
        for (int z = 0; z < 16; ++z) {
            const int ib = z / 4;
            bzc.off[z] = (long long)permc[ib] * DE * DE - (long long)ib * DE;
        }
    }
    k_gemm<64, 128, 4, 8, 16><<<dim3(16, 1, 16), 256, 0, stream>>>(
        Xc, 4 * DE, W_agg, DE, csum, DE, NC, DE, 4 * DE, 510, bzc);

    // 14) drug main GEMM: dsum = Xd @ [W2|W3|W5|W7]^T  (K=8160 as 4 windows of 2040)
    BZ bzd;
    {
        const int permd[4] = {2, 3, 5, 7};
        for (int z = 0; z < 16; ++z) bzd.off[z] = 0;
        for (int z = 0; z < 4; ++z) bzd.off[z] = (long long)permd[z] * DE * DE - (long long)z * DE;
    }
    k_gemm<128, 128, 8, 8, 16><<<dim3(16, 8, 4), 256, 0, stream>>>(
        Xd, 4 * DE, W_agg, DE, dsum, DE, ND, DE, 4 * DE, 2040, bzd);

    // 15) epilogue: relu((sum+b)*(emb+1)) in-place
    k_epi<<<8065, 256, 0, stream>>>(csum, dsum, embC, embD, b_agg);
    // 16) row stats for Pearson
    k_rowstats<<<NC + ND, 256, 0, stream>>>(csum, dsum, ws);
    // 17) corr + sigmoid -> out [60, 952]
    k_corr<<<dim3(60, 4), 256, 0, stream>>>(csum, dsum, ws, out);

    (void)in_sizes; (void)n_in; (void)out_size; (void)ws_size;
}

// Round 3
// 2123.375 us; speedup vs baseline: 1.6588x; 1.6588x over previous
//
#include <hip/hip_runtime.h>
#include <math.h>

#define NC 60
#define ND 952
#define DE 2040
#define NG 17737
#define NF 881
#define GAMMA_C 8.7f
#define EPS_BN 1e-5f

// ---- workspace layout (float offsets) ----
#define O_DX      0          // 60
#define O_DC      60         // 60
#define O_DY      120        // 952
#define O_DDV     1072       // 952
#define O_B4H     2024       // 60
#define O_A4H     2084       // 952
#define O_CMU     3036       // 60
#define O_CIS     3096       // 60
#define O_DMU     3156       // 952
#define O_DIS     4108       // 952
#define O_ZSC     5060       // 60
#define O_ZSH     5120       // 60
#define O_ADJT    5248       // 952*60 = 57120
#define O_EMBC    62368      // 60*2040   = 122400
#define O_EMBD    184768     // 952*2040  = 1942080
#define O_CSUM    2126848    // 122400
#define O_DSUM    2249248    // 1942080
#define O_XC      4191328    // 60*8160  = 489600
#define O_XD      4680928    // 952*8160 = 7768320
#define O_PS      12449248   // 8*60*2040 = 979200 partial slabs -> end 13428448 (53.7 MB)

typedef _Float16 f16;
typedef __attribute__((ext_vector_type(8))) _Float16 f16x8;
typedef __attribute__((ext_vector_type(4))) float f32x4;

struct Win { int aoff[16]; int boff[16]; int len[16]; };

__device__ __forceinline__ unsigned short f2h(float x) {
    f16 h = (f16)x;
    unsigned short u;
    __builtin_memcpy(&u, &h, 2);
    return u;
}

__device__ __forceinline__ float blockReduceSum(float v, float* red) {
    const int t = threadIdx.x;
    red[t] = v;
    __syncthreads();
    for (int off = 128; off > 0; off >>= 1) {
        if (t < off) red[t] += red[t + off];
        __syncthreads();
    }
    float r = red[0];
    __syncthreads();
    return r;
}

// ---- scalars: rs/cs/dx/dy/dc/dd, b4h, a4h, adj^T ----
__global__ __launch_bounds__(256) void k_pre(
    const float* __restrict__ adj, const float* __restrict__ ch,
    const float* __restrict__ dh, float* __restrict__ ws)
{
    __shared__ float red[256];
    const int b = blockIdx.x, t = threadIdx.x;
    if (b < NC) {
        const int c = b;
        float s = 0.f;
        for (int j = t; j < ND; j += 256) s += adj[c * ND + j];
        float rs = blockReduceSum(s, red) + 1.f;
        if (t == 0) { ws[O_DX + c] = rsqrtf(rs); ws[O_DC + c] = 1.f / rs + 1.f; }
        float s2 = (t < NC) ? ch[c * NC + t] : 0.f;
        float hs = blockReduceSum(s2, red) + 1.f;
        if (t == 0) ws[O_B4H + c] = 1.f / hs;
    } else if (b < NC + ND) {
        const int i = b - NC;
        float s = 0.f;
        for (int j = t; j < ND; j += 256) s += dh[i * ND + j];
        float hs = blockReduceSum(s, red) + 1.f;
        if (t == 0) ws[O_A4H + i] = 1.f / hs;
        float s2 = (t < NC) ? adj[t * ND + i] : 0.f;
        float cs = blockReduceSum(s2, red) + 1.f;
        if (t == 0) { ws[O_DY + i] = rsqrtf(cs); ws[O_DDV + i] = 1.f / cs + 1.f; }
    } else {
        const int idx = (b - NC - ND) * 256 + t;
        if (idx < ND * NC) {
            const int i = idx / NC, c = idx % NC;
            ws[O_ADJT + idx] = adj[c * ND + i];
        }
    }
}

// ---- z-norm stats per cell row: zsc = 1/sd (ddof=1), zsh = -mu/sd ----
__global__ __launch_bounds__(256) void k_zstats(
    const float* __restrict__ x, float* __restrict__ ws)
{
    __shared__ float r1[256];
    __shared__ float r2[256];
    const int c = blockIdx.x, t = threadIdx.x;
    const float* row = x + c * NG;
    float s = 0.f, q = 0.f;
    for (int j = t; j < NG; j += 256) { float v = row[j]; s += v; q += v * v; }
    r1[t] = s; r2[t] = q;
    __syncthreads();
    for (int off = 128; off > 0; off >>= 1) {
        if (t < off) { r1[t] += r1[t + off]; r2[t] += r2[t + off]; }
        __syncthreads();
    }
    if (t == 0) {
        const float mu = r1[0] / (float)NG;
        const float var = (r2[0] - (float)NG * mu * mu) / (float)(NG - 1);
        const float inv = rsqrtf(var);
        ws[O_ZSC + c] = inv;
        ws[O_ZSH + c] = -mu * inv;
    }
}

// ============================================================================
// MFMA fp16 GEMM, fp32->fp16 convert during LDS staging. Deterministic:
// no atomics. Per window zi: acc += A[m,k]*B[n,k] (BNNT=1, B row-major [N,K])
// or A[m,k]*B[k,n] (BNNT=0). A gets optional per-k scale (ksc) then per-row
// affine (asc/ash). Output: C = [base +] rsign*rsc[m]*acc. partial=1: window
// blockIdx.z only, store to slab C + z*M*ldc.
// Tile BMx128, BK=32, 4 waves 2x2, 16x16x32 MFMA.
// ============================================================================
template<int BM, int BNNT>
__global__ __launch_bounds__(256) void k_mgemm(
    const float* __restrict__ A, int lda,
    const float* __restrict__ B, int ldb,
    float* __restrict__ C, int ldc,
    int M, int N,
    const float* __restrict__ asc, const float* __restrict__ ash,
    const float* __restrict__ ksc,
    const float* __restrict__ rsc, float rsign,
    const float* __restrict__ base, int baseld,
    int nwin, int partial, Win w)
{
    constexpr int PSA = BM * 8 + 8;
    constexpr int PSB = 128 * 8 + 8;
    constexpr int MI = BM / 32;
    __shared__ __align__(16) unsigned short As[4 * PSA];
    __shared__ __align__(16) unsigned short Bs[4 * PSB];
    const int t = threadIdx.x;
    const int wv = t >> 6, ln = t & 63;
    const int wm = wv >> 1, wn = wv & 1;
    const int kg = ln >> 4, lm = ln & 15;
    const int m0 = blockIdx.y * BM;
    const int n0 = blockIdx.x * 128;

    f32x4 acc[MI][4];
#pragma unroll
    for (int i = 0; i < MI; ++i)
#pragma unroll
        for (int j = 0; j < 4; ++j) acc[i][j] = (f32x4){0.f, 0.f, 0.f, 0.f};

    const int z0 = partial ? (int)blockIdx.z : 0;
    const int z1 = partial ? (int)blockIdx.z + 1 : nwin;

    for (int zi = z0; zi < z1; ++zi) {
        const int Ab = w.aoff[zi];
        const int Bb = w.boff[zi];
        const int len = w.len[zi];
        for (int kb = 0; kb < len; kb += 32) {
            const bool tail = (kb + 32 > len);
            // ---- stage A (BM x 32) ----
#pragma unroll
            for (int q = 0; q < (BM * 8) / 256; ++q) {
                const int c = q * 256 + t;
                const int m = c >> 3, kc = c & 7;
                const int mg = m0 + m;
                const bool mok = (mg < M);
                const int k0 = kb + kc * 4;
                const float* Ap = A + Ab + (mok ? mg : 0) * lda + k0;
                float v0 = 0.f, v1 = 0.f, v2 = 0.f, v3 = 0.f;
                if (mok) {
                    if (!tail) {
                        v0 = Ap[0]; v1 = Ap[1]; v2 = Ap[2]; v3 = Ap[3];
                        if (ksc) { v0 *= ksc[k0]; v1 *= ksc[k0 + 1]; v2 *= ksc[k0 + 2]; v3 *= ksc[k0 + 3]; }
                        if (asc) {
                            const float s = asc[mg], h = ash[mg];
                            v0 = v0 * s + h; v1 = v1 * s + h; v2 = v2 * s + h; v3 = v3 * s + h;
                        }
                    } else {
                        const float s = asc ? asc[mg] : 1.f;
                        const float h = asc ? ash[mg] : 0.f;
                        if (k0 + 0 < len) { v0 = Ap[0]; if (ksc) v0 *= ksc[k0 + 0]; v0 = v0 * s + h; }
                        if (k0 + 1 < len) { v1 = Ap[1]; if (ksc) v1 *= ksc[k0 + 1]; v1 = v1 * s + h; }
                        if (k0 + 2 < len) { v2 = Ap[2]; if (ksc) v2 *= ksc[k0 + 2]; v2 = v2 * s + h; }
                        if (k0 + 3 < len) { v3 = Ap[3]; if (ksc) v3 *= ksc[k0 + 3]; v3 = v3 * s + h; }
                    }
                }
                uint2 pk;
                pk.x = (unsigned)f2h(v0) | ((unsigned)f2h(v1) << 16);
                pk.y = (unsigned)f2h(v2) | ((unsigned)f2h(v3) << 16);
                *(uint2*)&As[(kc >> 1) * PSA + m * 8 + (kc & 1) * 4] = pk;
            }
            // ---- stage B (128 x 32) ----
#pragma unroll
            for (int q = 0; q < 4; ++q) {
                const int c = q * 256 + t;
                int n, kc;
                if (BNNT) { n = c >> 3; kc = c & 7; }
                else      { n = c & 127; kc = c >> 7; }
                const int ng = n0 + n;
                const int k0 = kb + kc * 4;
                float v0 = 0.f, v1 = 0.f, v2 = 0.f, v3 = 0.f;
                if (ng < N) {
                    if (BNNT) {
                        const float* Bp = B + Bb + ng * ldb + k0;
                        if (!tail) { v0 = Bp[0]; v1 = Bp[1]; v2 = Bp[2]; v3 = Bp[3]; }
                        else {
                            if (k0 + 0 < len) v0 = Bp[0];
                            if (k0 + 1 < len) v1 = Bp[1];
                            if (k0 + 2 < len) v2 = Bp[2];
                            if (k0 + 3 < len) v3 = Bp[3];
                        }
                    } else {
                        const float* Bp = B + Bb + k0 * ldb + ng;
                        if (!tail) { v0 = Bp[0]; v1 = Bp[ldb]; v2 = Bp[2 * ldb]; v3 = Bp[3 * ldb]; }
                        else {
                            if (k0 + 0 < len) v0 = Bp[0];
                            if (k0 + 1 < len) v1 = Bp[ldb];
                            if (k0 + 2 < len) v2 = Bp[2 * ldb];
                            if (k0 + 3 < len) v3 = Bp[3 * ldb];
                        }
                    }
                }
                uint2 pk;
                pk.x = (unsigned)f2h(v0) | ((unsigned)f2h(v1) << 16);
                pk.y = (unsigned)f2h(v2) | ((unsigned)f2h(v3) << 16);
                *(uint2*)&Bs[(kc >> 1) * PSB + n * 8 + (kc & 1) * 4] = pk;
            }
            __syncthreads();
            // ---- MFMA over the 32-deep K slab ----
            f16x8 af[MI], bfr[4];
#pragma unroll
            for (int i = 0; i < MI; ++i)
                af[i] = *(f16x8*)&As[kg * PSA + (wm * (BM / 2) + i * 16 + lm) * 8];
#pragma unroll
            for (int j = 0; j < 4; ++j)
                bfr[j] = *(f16x8*)&Bs[kg * PSB + (wn * 64 + j * 16 + lm) * 8];
#pragma unroll
            for (int i = 0; i < MI; ++i)
#pragma unroll
                for (int j = 0; j < 4; ++j)
                    acc[i][j] = __builtin_amdgcn_mfma_f32_16x16x32_f16(
                        af[i], bfr[j], acc[i][j], 0, 0, 0);
            __syncthreads();
        }
    }
    // ---- epilogue: direct store (no atomics) ----
    float* Cp = C + (partial ? (size_t)blockIdx.z * (size_t)M * (size_t)ldc : (size_t)0);
#pragma unroll
    for (int i = 0; i < MI; ++i) {
        const int mb = m0 + wm * (BM / 2) + i * 16 + kg * 4;
#pragma unroll
        for (int r = 0; r < 4; ++r) {
            const int m = mb + r;
            if (m >= M) continue;
            const float rf = rsign * (rsc ? rsc[m] : 1.f);
#pragma unroll
            for (int j = 0; j < 4; ++j) {
                const int n = n0 + wn * 64 + j * 16 + lm;
                if (n < N) {
                    float v = rf * acc[i][j][r];
                    if (base) v += base[m * baseld + n];
                    Cp[(size_t)m * ldc + n] = v;
                }
            }
        }
    }
}

// ---- fixed-order reduction of Z partial slabs ----
__global__ __launch_bounds__(256) void k_reduce(
    const float* __restrict__ P, float* __restrict__ out, int Z, int slab, int n)
{
    const int i = blockIdx.x * 256 + threadIdx.x;
    if (i < n) {
        float s = 0.f;
        for (int z = 0; z < Z; ++z) s += P[(size_t)z * slab + i];
        out[i] = s;
    }
}

// ---- BatchNorm over rows (training stats, biased var), in-place ----
__global__ __launch_bounds__(256) void k_bncols(
    float* __restrict__ X, int R,
    const float* __restrict__ g, const float* __restrict__ bta)
{
    const int d = blockIdx.x * 256 + threadIdx.x;
    if (d >= DE) return;
    float s = 0.f, q = 0.f;
    for (int r = 0; r < R; ++r) { float v = X[r * DE + d]; s += v; q += v * v; }
    const float mu = s / (float)R;
    float var = q / (float)R - mu * mu;
    var = fmaxf(var, 0.f);
    const float sc = rsqrtf(var + EPS_BN) * g[d];
    const float sh = bta[d] - mu * sc;
    for (int r = 0; r < R; ++r) {
        const int ix = r * DE + d;
        X[ix] = X[ix] * sc + sh;
    }
}

// ---- Xc/Xd block0 = diag-scaled emb ----
__global__ __launch_bounds__(256) void k_buildX(
    const float* __restrict__ embC, const float* __restrict__ embD,
    const float* __restrict__ dc, const float* __restrict__ dd,
    float* __restrict__ Xc, float* __restrict__ Xd)
{
    const int idx = blockIdx.x * 256 + threadIdx.x;
    const int nc = NC * DE;
    const int ndd = ND * DE;
    if (idx < nc) {
        const int c = idx / DE, d = idx % DE;
        Xc[c * (4 * DE) + d] = dc[c] * embC[idx];
    } else if (idx < nc + ndd) {
        const int k = idx - nc;
        const int i = k / DE, d = k % DE;
        Xd[i * (4 * DE) + d] = dd[i] * embD[k];
    }
}

// ---- epilogue: agg = relu((sum + bias)*(emb+1)) in-place ----
__global__ __launch_bounds__(256) void k_epi(
    float* __restrict__ csum, float* __restrict__ dsum,
    const float* __restrict__ embC, const float* __restrict__ embD,
    const float* __restrict__ b_agg)
{
    const int idx = blockIdx.x * 256 + threadIdx.x;
    const int nc = NC * DE;
    const int ndd = ND * DE;
    if (idx < nc) {
        const int d = idx % DE;
        const float bc = b_agg[0 * DE + d] + b_agg[1 * DE + d] + b_agg[4 * DE + d] + b_agg[6 * DE + d];
        const float v = (csum[idx] + bc) * (embC[idx] + 1.f);
        csum[idx] = fmaxf(v, 0.f);
    } else if (idx < nc + ndd) {
        const int k = idx - nc;
        const int d = k % DE;
        const float bd = b_agg[2 * DE + d] + b_agg[3 * DE + d] + b_agg[5 * DE + d] + b_agg[7 * DE + d];
        const float v = (dsum[k] + bd) * (embD[k] + 1.f);
        dsum[k] = fmaxf(v, 0.f);
    }
}

// ---- per-row mean + 1/||x-mu|| for corr ----
__global__ __launch_bounds__(256) void k_rowstats(
    const float* __restrict__ cagg, const float* __restrict__ dagg,
    float* __restrict__ ws)
{
    __shared__ float red[256];
    const int b = blockIdx.x, t = threadIdx.x;
    const float* row;
    int omu, ois;
    if (b < NC) { row = cagg + b * DE; omu = O_CMU + b; ois = O_CIS + b; }
    else { const int i = b - NC; row = dagg + i * DE; omu = O_DMU + i; ois = O_DIS + i; }
    float s = 0.f;
    for (int j = t; j < DE; j += 256) s += row[j];
    const float mu = blockReduceSum(s, red) / (float)DE;
    float q = 0.f;
    for (int j = t; j < DE; j += 256) { const float v = row[j] - mu; q += v * v; }
    const float ss = blockReduceSum(q, red);
    if (t == 0) { ws[omu] = mu; ws[ois] = rsqrtf(ss); }
}

// ---- corr + sigmoid ----
__global__ __launch_bounds__(256) void k_corr(
    const float* __restrict__ cagg, const float* __restrict__ dagg,
    const float* __restrict__ ws, float* __restrict__ out)
{
    const int KT = 32;
    __shared__ float xs[16][KT + 1];
    __shared__ float ys[16][KT + 1];
    const int t = threadIdx.x;
    const int tcr = t >> 4, ti = t & 15;
    const int c0 = blockIdx.y * 16, i0 = blockIdx.x * 16;
    float acc = 0.f;
    for (int kb = 0; kb < DE; kb += KT) {
#pragma unroll
        for (int q = 0; q < 2; ++q) {
            const int s = q * 256 + t;
            const int row = s >> 5, kk = s & 31;
            const int k = kb + kk;
            const int c = c0 + row;
            xs[row][kk] = (c < NC && k < DE) ? cagg[c * DE + k] : 0.f;
            const int i = i0 + row;
            ys[row][kk] = (i < ND && k < DE) ? dagg[i * DE + k] : 0.f;
        }
        __syncthreads();
#pragma unroll
        for (int kt = 0; kt < KT; ++kt) acc += xs[tcr][kt] * ys[ti][kt];
        __syncthreads();
    }
    const int c = c0 + tcr, i = i0 + ti;
    if (c < NC && i < ND) {
        const float num = acc - (float)DE * ws[O_CMU + c] * ws[O_DMU + i];
        const float corr = num * ws[O_CIS + c] * ws[O_DIS + i];
        out[c * ND + i] = 1.f / (1.f + expf(-GAMMA_C * corr));
    }
}

static inline Win win1(int len) {
    Win w;
    for (int z = 0; z < 16; ++z) { w.aoff[z] = 0; w.boff[z] = 0; w.len[z] = 0; }
    w.len[0] = len;
    return w;
}

extern "C" void kernel_launch(void* const* d_in, const int* in_sizes, int n_in,
                              void* d_out, int out_size, void* d_ws, size_t ws_size,
                              hipStream_t stream)
{
    const float* adj         = (const float*)d_in[0];
    const float* cell_exprs  = (const float*)d_in[1];
    const float* drug_finger = (const float*)d_in[2];
    const float* cell_hyper  = (const float*)d_in[3];
    const float* drug_hyper  = (const float*)d_in[4];
    const float* W_agg       = (const float*)d_in[5];
    const float* b_agg       = (const float*)d_in[6];
    const float* ldd_w       = (const float*)d_in[7];
    const float* lcc_w       = (const float*)d_in[9];
    const float* bnd_g       = (const float*)d_in[11];
    const float* bnd_b       = (const float*)d_in[12];
    const float* bnc_g       = (const float*)d_in[13];
    const float* bnc_b       = (const float*)d_in[14];
    float* ws  = (float*)d_ws;
    float* out = (float*)d_out;

    float* embC = ws + O_EMBC;
    float* embD = ws + O_EMBD;
    float* csum = ws + O_CSUM;
    float* dsum = ws + O_DSUM;
    float* Xc   = ws + O_XC;
    float* Xd   = ws + O_XD;
    float* PS   = ws + O_PS;

    // 1) scalars + adj^T
    k_pre<<<1236, 256, 0, stream>>>(adj, cell_hyper, drug_hyper, ws);
    // 2) z-norm stats (folded into exp GEMM A-staging as row affine)
    k_zstats<<<NC, 256, 0, stream>>>(cell_exprs, ws);

    // 3) exp = znorm(cell_exprs) @ lcc_w^T : 8 K-windows -> partial slabs -> reduce
    {
        Win w;
        for (int z = 0; z < 16; ++z) { w.aoff[z] = 0; w.boff[z] = 0; w.len[z] = 0; }
        for (int z = 0; z < 8; ++z) {
            w.aoff[z] = z * 2224;
            w.boff[z] = z * 2224;
            int l = NG - z * 2224;
            w.len[z] = l > 2224 ? 2224 : l;
        }
        k_mgemm<64, 1><<<dim3(16, 1, 8), 256, 0, stream>>>(
            cell_exprs, NG, lcc_w, NG, PS, DE, NC, DE,
            ws + O_ZSC, ws + O_ZSH, nullptr, nullptr, 1.f, nullptr, 0, 8, 1, w);
        k_reduce<<<479, 256, 0, stream>>>(PS, embC, 8, NC * DE, NC * DE);
    }
    // 4) fig = drug_finger @ ldd_w^T (direct, deterministic)
    k_mgemm<32, 1><<<dim3(16, 30, 1), 256, 0, stream>>>(
        drug_finger, NF, ldd_w, NF, embD, DE, ND, DE,
        nullptr, nullptr, nullptr, nullptr, 1.f, nullptr, 0, 1, 0, win1(NF));
    // 5) BatchNorm (ldd_b/lcc_b cancel in BN mean-subtraction)
    k_bncols<<<8, 256, 0, stream>>>(embC, NC, bnc_g, bnc_b);
    k_bncols<<<8, 256, 0, stream>>>(embD, ND, bnd_g, bnd_b);
    // 6) Xc/Xd block0 = diag*emb
    k_buildX<<<8065, 256, 0, stream>>>(embC, embD, ws + O_DC, ws + O_DDV, Xc, Xd);

    // 7) X1 = dx.*(adj@(dy.*fig))
    k_mgemm<64, 0><<<dim3(16, 1, 1), 256, 0, stream>>>(
        adj, ND, embD, DE, Xc + DE, 4 * DE, NC, DE,
        nullptr, nullptr, ws + O_DY, ws + O_DX, 1.f, nullptr, 0, 1, 0, win1(ND));
    // 8) X3 = dy.*(adjT@(dx.*exp))
    k_mgemm<32, 0><<<dim3(16, 30, 1), 256, 0, stream>>>(
        ws + O_ADJT, NC, embC, DE, Xd + DE, 4 * DE, ND, DE,
        nullptr, nullptr, ws + O_DX, ws + O_DY, 1.f, nullptr, 0, 1, 0, win1(NC));
    // 9) X4 = cell_hyper @ exp
    k_mgemm<64, 0><<<dim3(16, 1, 1), 256, 0, stream>>>(
        cell_hyper, NC, embC, DE, Xc + 2 * DE, 4 * DE, NC, DE,
        nullptr, nullptr, nullptr, nullptr, 1.f, nullptr, 0, 1, 0, win1(NC));
    // 10) X6 = exp - b4h.*(CH@(b4h.*exp))  [base epilogue, no atomics]
    k_mgemm<64, 0><<<dim3(16, 1, 1), 256, 0, stream>>>(
        cell_hyper, NC, embC, DE, Xc + 3 * DE, 4 * DE, NC, DE,
        nullptr, nullptr, ws + O_B4H, ws + O_B4H, -1.f, embC, DE, 1, 0, win1(NC));
    // 11) X5 = drug_hyper @ fig
    k_mgemm<32, 0><<<dim3(16, 30, 1), 256, 0, stream>>>(
        drug_hyper, ND, embD, DE, Xd + 2 * DE, 4 * DE, ND, DE,
        nullptr, nullptr, nullptr, nullptr, 1.f, nullptr, 0, 1, 0, win1(ND));
    // 12) X7 = fig - a4h.*(DH@(a4h.*fig))
    k_mgemm<32, 0><<<dim3(16, 30, 1), 256, 0, stream>>>(
        drug_hyper, ND, embD, DE, Xd + 3 * DE, 4 * DE, ND, DE,
        nullptr, nullptr, ws + O_A4H, ws + O_A4H, -1.f, embD, DE, 1, 0, win1(ND));

    // 13) cell main: csum = Xc @ [W0|W1|W4|W6]^T : 8 windows -> slabs -> reduce
    {
        const int permc[4] = {0, 1, 4, 6};
        Win w;
        for (int z = 0; z < 16; ++z) { w.aoff[z] = 0; w.boff[z] = 0; w.len[z] = 0; }
        for (int z = 0; z < 8; ++z) {
            const int ib = z >> 1, sub = z & 1;
            w.aoff[z] = ib * DE + sub * 1020;
            w.boff[z] = permc[ib] * DE * DE + sub * 1020;
            w.len[z] = 1020;
        }
        k_mgemm<64, 1><<<dim3(16, 1, 8), 256, 0, stream>>>(
            Xc, 4 * DE, W_agg, DE, PS, DE, NC, DE,
            nullptr, nullptr, nullptr, nullptr, 1.f, nullptr, 0, 8, 1, w);
        k_reduce<<<479, 256, 0, stream>>>(PS, csum, 8, NC * DE, NC * DE);
    }
    // 14) drug main: dsum = Xd @ [W2|W3|W5|W7]^T : 4 windows looped in-kernel
    {
        const int permd[4] = {2, 3, 5, 7};
        Win w;
        for (int z = 0; z < 16; ++z) { w.aoff[z] = 0; w.boff[z] = 0; w.len[z] = 0; }
        for (int z = 0; z < 4; ++z) {
            w.aoff[z] = z * DE;
            w.boff[z] = permd[z] * DE * DE;
            w.len[z] = DE;
        }
        k_mgemm<32, 1><<<dim3(16, 30, 1), 256, 0, stream>>>(
            Xd, 4 * DE, W_agg, DE, dsum, DE, ND, DE,
            nullptr, nullptr, nullptr, nullptr, 1.f, nullptr, 0, 4, 0, w);
    }

    // 15) epilogue: relu((sum+b)*(emb+1))
    k_epi<<<8065, 256, 0, stream>>>(csum, dsum, embC, embD, b_agg);
    // 16) row stats for Pearson
    k_rowstats<<<NC + ND, 256, 0, stream>>>(csum, dsum, ws);
    // 17) corr + sigmoid -> out [60, 952]
    k_corr<<<dim3(60, 4), 256, 0, stream>>>(csum, dsum, ws, out);

    (void)in_sizes; (void)n_in; (void)out_size; (void)ws_size;
}

// Round 4
// 1751.621 us; speedup vs baseline: 2.0109x; 1.2122x over previous
//
#include <hip/hip_runtime.h>
#include <math.h>

#define NC 60
#define ND 952
#define DE 2040
#define NG 17737
#define NF 881
#define GAMMA_C 8.7f
#define EPS_BN 1e-5f

// ---- fp32 workspace layout (float offsets) ----
#define O_DX      0
#define O_DC      64
#define O_DY      128
#define O_DDV     1088
#define O_B4H     2048
#define O_A4H     2112
#define O_CMU     3072
#define O_CIS     3136
#define O_DMU     3200
#define O_DIS     4160
#define O_ZSC     5120
#define O_ZSH     5184
#define O_EMBC    8000       // 60*2040   = 122400
#define O_EMBD    130400     // 952*2040  = 1942080
#define O_CSUM    2072480    // 122400
#define O_DSUM    2194880    // 1942080
#define O_PS      4136960    // 10*122400 = 1224000 (slabs, reused)
#define O_H16     5360960    // fp16 pool starts here (float offset, 16B aligned)
// total floats: 5360960 + 8023680 = 13384640 -> 53.5 MB

// ---- fp16 pool layout (half offsets, all mult of 8) ----
#define H_CX    0            // 60*17760   = 1065600 (znormed cell_exprs, K-pad)
#define H_DF    1065600      // 952*896    = 852992  (drug_finger, K-pad)
#define H_LDW   1918592      // 2040*896   = 1827840 (ldd_w, K-pad)
#define H_ALC   3746432      // 60*960     = 57600   (dx.*adj.*dy)
#define H_ALD   3804032      // 952*64     = 60928   (dy.*adjT.*dx)
#define H_CH    3864960      // 60*64      = 3840
#define H_CHS   3868800      // 60*64      = 3840    (b4h.*CH.*b4h)
#define H_DH    3872640      // 952*960    = 913920
#define H_DHS   4786560      // 952*960    = 913920  (a4h.*DH.*a4h)
#define H_FIGT  5700480      // 2040*960   = 1958400 (fig^T, pad)
#define H_EXPT  7658880      // 2040*64    = 130560  (exp^T, pad)
#define H_XC    7789440      // 60*8160    = 489600
#define H_XD    8279040      // 952*8160   = 7768320 -> end 16047360 halves

typedef _Float16 f16;
typedef __attribute__((ext_vector_type(8))) _Float16 f16x8;
typedef __attribute__((ext_vector_type(4))) float f32x4;

struct Job {
    int aoff[16]; int boff[16]; int lda[16]; int ldb[16];
    int len[16]; int blim[16]; int coff[16]; int bflag[16];
    float rsg[16];
};

__device__ __forceinline__ float blockReduceSum(float v, float* red) {
    const int t = threadIdx.x;
    red[t] = v;
    __syncthreads();
    for (int off = 128; off > 0; off >>= 1) {
        if (t < off) red[t] += red[t + off];
        __syncthreads();
    }
    float r = red[0];
    __syncthreads();
    return r;
}

// ---- scalars: dx/dc/dy/ddv, b4h, a4h ----
__global__ __launch_bounds__(256) void k_pre(
    const float* __restrict__ adj, const float* __restrict__ ch,
    const float* __restrict__ dh, float* __restrict__ ws)
{
    __shared__ float red[256];
    const int b = blockIdx.x, t = threadIdx.x;
    if (b < NC) {
        const int c = b;
        float s = 0.f;
        for (int j = t; j < ND; j += 256) s += adj[c * ND + j];
        float rs = blockReduceSum(s, red) + 1.f;
        if (t == 0) { ws[O_DX + c] = rsqrtf(rs); ws[O_DC + c] = 1.f / rs + 1.f; }
        float s2 = (t < NC) ? ch[c * NC + t] : 0.f;
        float hs = blockReduceSum(s2, red) + 1.f;
        if (t == 0) ws[O_B4H + c] = 1.f / hs;
    } else {
        const int i = b - NC;
        float s = 0.f;
        for (int j = t; j < ND; j += 256) s += dh[i * ND + j];
        float hs = blockReduceSum(s, red) + 1.f;
        if (t == 0) ws[O_A4H + i] = 1.f / hs;
        float s2 = (t < NC) ? adj[t * ND + i] : 0.f;
        float cs = blockReduceSum(s2, red) + 1.f;
        if (t == 0) { ws[O_DY + i] = rsqrtf(cs); ws[O_DDV + i] = 1.f / cs + 1.f; }
    }
}

// ---- z-norm stats per cell row ----
__global__ __launch_bounds__(256) void k_zstats(
    const float* __restrict__ x, float* __restrict__ ws)
{
    __shared__ float r1[256];
    __shared__ float r2[256];
    const int c = blockIdx.x, t = threadIdx.x;
    const float* row = x + c * NG;
    float s = 0.f, q = 0.f;
    for (int j = t; j < NG; j += 256) { float v = row[j]; s += v; q += v * v; }
    r1[t] = s; r2[t] = q;
    __syncthreads();
    for (int off = 128; off > 0; off >>= 1) {
        if (t < off) { r1[t] += r1[t + off]; r2[t] += r2[t + off]; }
        __syncthreads();
    }
    if (t == 0) {
        const float mu = r1[0] / (float)NG;
        const float var = (r2[0] - (float)NG * mu * mu) / (float)(NG - 1);
        const float inv = rsqrtf(var);
        ws[O_ZSC + c] = inv;
        ws[O_ZSH + c] = -mu * inv;
    }
}

// ---- convert/pad/scale-fold all small fp16 operands in one pass ----
#define CVT_TOT 5700480
__global__ __launch_bounds__(256) void k_cvt(
    const float* __restrict__ ce, const float* __restrict__ dfing,
    const float* __restrict__ ldw, const float* __restrict__ adj,
    const float* __restrict__ chyp, const float* __restrict__ dhyp,
    const float* __restrict__ ws, f16* __restrict__ h16)
{
    const float* dx = ws + O_DX;
    const float* dy = ws + O_DY;
    const float* b4h = ws + O_B4H;
    const float* a4h = ws + O_A4H;
    const float* zsc = ws + O_ZSC;
    const float* zsh = ws + O_ZSH;
    for (int idx = blockIdx.x * 256 + threadIdx.x; idx < CVT_TOT;
         idx += gridDim.x * 256) {
        float v = 0.f;
        if (idx < H_DF) {                     // cx16: znormed cell_exprs
            const int c = idx / 17760, k = idx % 17760;
            if (k < NG) v = ce[c * NG + k] * zsc[c] + zsh[c];
        } else if (idx < H_LDW) {             // df16
            const int j = idx - H_DF;
            const int i = j / 896, k = j % 896;
            if (k < NF) v = dfing[i * NF + k];
        } else if (idx < H_ALC) {             // ldw16
            const int j = idx - H_LDW;
            const int d = j / 896, k = j % 896;
            if (k < NF) v = ldw[d * NF + k];
        } else if (idx < H_ALD) {             // aggLc
            const int j = idx - H_ALC;
            const int c = j / 960, i = j % 960;
            if (i < ND) v = dx[c] * adj[c * ND + i] * dy[i];
        } else if (idx < H_CH) {              // aggLd
            const int j = idx - H_ALD;
            const int i = j / 64, c = j % 64;
            if (c < NC) v = dy[i] * adj[c * ND + i] * dx[c];
        } else if (idx < H_CHS) {             // ch16
            const int j = idx - H_CH;
            const int c = j / 64, k = j % 64;
            if (k < NC) v = chyp[c * NC + k];
        } else if (idx < H_DH) {              // chs16
            const int j = idx - H_CHS;
            const int c = j / 64, k = j % 64;
            if (k < NC) v = b4h[c] * chyp[c * NC + k] * b4h[k];
        } else if (idx < H_DHS) {             // dh16
            const int j = idx - H_DH;
            const int i = j / 960, k = j % 960;
            if (k < ND) v = dhyp[i * ND + k];
        } else {                              // dhs16
            const int j = idx - H_DHS;
            const int i = j / 960, k = j % 960;
            if (k < ND) v = a4h[i] * dhyp[i * ND + k] * a4h[k];
        }
        h16[idx] = (f16)v;
    }
}

// ============================================================================
// Unified fp16 MFMA NT GEMM with job table.
//   acc[m,n] = sum over windows of A16[m,k] * B[n,k]
//   BMODE: 0 = B fp16 (aligned), 1 = B fp32 aligned (uint4), 2 = B fp32
//          unaligned/scalar with real-K limit blim.
//   partial=1: blockIdx.z picks one job; else loop jobs 0..nwin-1.
//   Epilogue: v = rsg*acc (+ base[m,n] if bflag); store fp32 (ws+coff) or
//   fp16 (h16+coff) per F16OUT. Deterministic, no atomics.
// Tile BMxBN, 4 waves 2x2, KT=32, 16x16x32 f16 MFMA.
// ============================================================================
template<int BM, int BN, int BMODE, int F16OUT>
__global__ __launch_bounds__(256) void k_fgemm(
    const f16* __restrict__ Ah, const void* __restrict__ Bp,
    float* __restrict__ ws, f16* __restrict__ h16,
    const float* __restrict__ basep, int baseld,
    int M, int N, int ldc, int nwin, int partial, Job jb)
{
    constexpr int PSA = BM * 8 + 8;
    constexpr int PSB = BN * 8 + 8;
    constexpr int MI = BM / 32;
    constexpr int NI = BN / 32;
    __shared__ __align__(16) unsigned short As[4 * PSA];
    __shared__ __align__(16) unsigned short Bs[4 * PSB];
    const int t = threadIdx.x;
    const int wv = t >> 6, ln = t & 63;
    const int wm = wv >> 1, wn = wv & 1;
    const int kg = ln >> 4, lm = ln & 15;
    const int m0 = blockIdx.y * BM;
    const int n0 = blockIdx.x * BN;

    f32x4 acc[MI][NI];
#pragma unroll
    for (int i = 0; i < MI; ++i)
#pragma unroll
        for (int j = 0; j < NI; ++j) acc[i][j] = (f32x4){0.f, 0.f, 0.f, 0.f};

    const int z0 = partial ? (int)blockIdx.z : 0;
    const int z1 = partial ? (int)blockIdx.z + 1 : nwin;

    for (int zi = z0; zi < z1; ++zi) {
        const int Ab = jb.aoff[zi], Bb = jb.boff[zi];
        const int lda = jb.lda[zi], ldb = jb.ldb[zi];
        const int len = jb.len[zi], bl = jb.blim[zi];
        for (int kb = 0; kb < len; kb += 32) {
            // ---- stage A (BM x 32 halves), uint4 chunks of 8 halves ----
#pragma unroll
            for (int p = 0; p < (BM * 4) / 256; ++p) {
                const int ci = p * 256 + t;
                const int m = ci >> 2, kc = ci & 3;
                const int k0 = kb + kc * 8;
                uint4 d = {0u, 0u, 0u, 0u};
                if (m0 + m < M && k0 < len)
                    d = *(const uint4*)(Ah + Ab + (m0 + m) * lda + k0);
                *(uint4*)&As[kc * PSA + m * 8] = d;
            }
            // ---- stage B (BN x 32) ----
#pragma unroll
            for (int p = 0; p < (BN * 4) / 256; ++p) {
                const int ci = p * 256 + t;
                const int n = ci >> 2, kc = ci & 3;
                const int k0 = kb + kc * 8;
                const bool ok = (n0 + n < N) && (k0 < len);
                if (BMODE == 0) {
                    uint4 d = {0u, 0u, 0u, 0u};
                    if (ok) d = *(const uint4*)((const f16*)Bp + Bb + (n0 + n) * ldb + k0);
                    *(uint4*)&Bs[kc * PSB + n * 8] = d;
                } else if (BMODE == 1) {
                    f16x8 pk = (f16x8)(f16)0.f;
                    if (ok) {
                        const float* bq = (const float*)Bp + Bb + (n0 + n) * ldb + k0;
                        const float4 x = *(const float4*)bq;
                        const float4 y = *(const float4*)(bq + 4);
                        pk[0] = (f16)x.x; pk[1] = (f16)x.y; pk[2] = (f16)x.z; pk[3] = (f16)x.w;
                        pk[4] = (f16)y.x; pk[5] = (f16)y.y; pk[6] = (f16)y.z; pk[7] = (f16)y.w;
                    }
                    *(f16x8*)&Bs[kc * PSB + n * 8] = pk;
                } else {
                    f16x8 pk = (f16x8)(f16)0.f;
                    if (n0 + n < N) {
                        const float* bq = (const float*)Bp + Bb + (n0 + n) * ldb + k0;
#pragma unroll
                        for (int e = 0; e < 8; ++e)
                            if (k0 + e < bl) pk[e] = (f16)bq[e];
                    }
                    *(f16x8*)&Bs[kc * PSB + n * 8] = pk;
                }
            }
            __syncthreads();
            f16x8 af[MI], bfr[NI];
#pragma unroll
            for (int i = 0; i < MI; ++i)
                af[i] = *(f16x8*)&As[kg * PSA + (wm * (BM / 2) + i * 16 + lm) * 8];
#pragma unroll
            for (int j = 0; j < NI; ++j)
                bfr[j] = *(f16x8*)&Bs[kg * PSB + (wn * (BN / 2) + j * 16 + lm) * 8];
#pragma unroll
            for (int i = 0; i < MI; ++i)
#pragma unroll
                for (int j = 0; j < NI; ++j)
                    acc[i][j] = __builtin_amdgcn_mfma_f32_16x16x32_f16(
                        af[i], bfr[j], acc[i][j], 0, 0, 0);
            __syncthreads();
        }
    }
    // ---- epilogue ----
    const int zz = partial ? (int)blockIdx.z : 0;
    const float rs = jb.rsg[zz];
    const int co = jb.coff[zz];
    const int bfl = jb.bflag[zz];
#pragma unroll
    for (int i = 0; i < MI; ++i) {
        const int mb = m0 + wm * (BM / 2) + i * 16 + kg * 4;
#pragma unroll
        for (int r = 0; r < 4; ++r) {
            const int m = mb + r;
            if (m >= M) continue;
#pragma unroll
            for (int j = 0; j < NI; ++j) {
                const int n = n0 + wn * (BN / 2) + j * 16 + lm;
                if (n >= N) continue;
                float v = rs * acc[i][j][r];
                if (bfl) v += basep[m * baseld + n];
                if (F16OUT) h16[co + m * ldc + n] = (f16)v;
                else        ws[co + m * ldc + n] = v;
            }
        }
    }
}

// ---- fixed-order reduction of Z partial slabs ----
__global__ __launch_bounds__(256) void k_reduce(
    const float* __restrict__ P, float* __restrict__ out, int Z, int slab, int n)
{
    const int i = blockIdx.x * 256 + threadIdx.x;
    if (i < n) {
        float s = 0.f;
        for (int z = 0; z < Z; ++z) s += P[z * slab + i];
        out[i] = s;
    }
}

// ---- BatchNorm (train stats) in-place + transposed fp16 copy w/ pads ----
__global__ __launch_bounds__(256) void k_bn(
    float* __restrict__ ws, f16* __restrict__ h16,
    const float* __restrict__ cg, const float* __restrict__ cb,
    const float* __restrict__ dg, const float* __restrict__ db)
{
    const int id = blockIdx.x * 256 + threadIdx.x;
    if (id >= 2 * DE) return;
    float* X; f16* T; const float* g; const float* b; int R, Rp, ldT, d;
    if (id < DE) { d = id; X = ws + O_EMBC; T = h16 + H_EXPT; g = cg; b = cb; R = NC; Rp = 64; ldT = 64; }
    else { d = id - DE; X = ws + O_EMBD; T = h16 + H_FIGT; g = dg; b = db; R = ND; Rp = 960; ldT = 960; }
    float s = 0.f, q = 0.f;
    for (int r = 0; r < R; ++r) { const float v = X[r * DE + d]; s += v; q += v * v; }
    const float mu = s / (float)R;
    float var = q / (float)R - mu * mu;
    var = fmaxf(var, 0.f);
    const float sc = rsqrtf(var + EPS_BN) * g[d];
    const float sh = b[d] - mu * sc;
    for (int r = 0; r < Rp; ++r) {
        if (r < R) {
            const float v = X[r * DE + d] * sc + sh;
            X[r * DE + d] = v;
            T[d * ldT + r] = (f16)v;
        } else {
            T[d * ldT + r] = (f16)0.f;
        }
    }
}

// ---- Xc/Xd block0 = diag-scaled emb (fp16) ----
__global__ __launch_bounds__(256) void k_buildX(
    const float* __restrict__ ws, f16* __restrict__ h16)
{
    const int idx = blockIdx.x * 256 + threadIdx.x;
    if (idx < NC * DE) {
        const int c = idx / DE, d = idx % DE;
        h16[H_XC + c * (4 * DE) + d] = (f16)(ws[O_DC + c] * ws[O_EMBC + idx]);
    } else if (idx < (NC + ND) * DE) {
        const int k = idx - NC * DE;
        const int i = k / DE, d = k % DE;
        h16[H_XD + i * (4 * DE) + d] = (f16)(ws[O_DDV + i] * ws[O_EMBD + k]);
    }
}

// ---- epilogue: agg = relu((sum + bias)*(emb+1)) in-place ----
__global__ __launch_bounds__(256) void k_epi(
    float* __restrict__ ws, const float* __restrict__ b_agg)
{
    const int idx = blockIdx.x * 256 + threadIdx.x;
    if (idx < NC * DE) {
        const int d = idx % DE;
        const float bc = b_agg[0 * DE + d] + b_agg[1 * DE + d] + b_agg[4 * DE + d] + b_agg[6 * DE + d];
        const float v = (ws[O_CSUM + idx] + bc) * (ws[O_EMBC + idx] + 1.f);
        ws[O_CSUM + idx] = fmaxf(v, 0.f);
    } else if (idx < (NC + ND) * DE) {
        const int k = idx - NC * DE;
        const int d = k % DE;
        const float bd = b_agg[2 * DE + d] + b_agg[3 * DE + d] + b_agg[5 * DE + d] + b_agg[7 * DE + d];
        const float v = (ws[O_DSUM + k] + bd) * (ws[O_EMBD + k] + 1.f);
        ws[O_DSUM + k] = fmaxf(v, 0.f);
    }
}

// ---- per-row mean + 1/||x-mu|| ----
__global__ __launch_bounds__(256) void k_rowstats(float* __restrict__ ws)
{
    __shared__ float red[256];
    const int b = blockIdx.x, t = threadIdx.x;
    const float* row;
    int omu, ois;
    if (b < NC) { row = ws + O_CSUM + b * DE; omu = O_CMU + b; ois = O_CIS + b; }
    else { const int i = b - NC; row = ws + O_DSUM + i * DE; omu = O_DMU + i; ois = O_DIS + i; }
    float s = 0.f;
    for (int j = t; j < DE; j += 256) s += row[j];
    const float mu = blockReduceSum(s, red) / (float)DE;
    float q = 0.f;
    for (int j = t; j < DE; j += 256) { const float v = row[j] - mu; q += v * v; }
    const float ss = blockReduceSum(q, red);
    if (t == 0) { ws[omu] = mu; ws[ois] = rsqrtf(ss); }
}

// ---- corr + sigmoid ----
__global__ __launch_bounds__(256) void k_corr(
    const float* __restrict__ ws, float* __restrict__ out)
{
    const int KT = 32;
    __shared__ float xs[16][KT + 1];
    __shared__ float ys[16][KT + 1];
    const int t = threadIdx.x;
    const int tcr = t >> 4, ti = t & 15;
    const int c0 = blockIdx.y * 16, i0 = blockIdx.x * 16;
    float acc = 0.f;
    for (int kb = 0; kb < DE; kb += KT) {
#pragma unroll
        for (int q = 0; q < 2; ++q) {
            const int s = q * 256 + t;
            const int row = s >> 5, kk = s & 31;
            const int k = kb + kk;
            const int c = c0 + row;
            xs[row][kk] = (c < NC && k < DE) ? ws[O_CSUM + c * DE + k] : 0.f;
            const int i = i0 + row;
            ys[row][kk] = (i < ND && k < DE) ? ws[O_DSUM + i * DE + k] : 0.f;
        }
        __syncthreads();
#pragma unroll
        for (int kt = 0; kt < KT; ++kt) acc += xs[tcr][kt] * ys[ti][kt];
        __syncthreads();
    }
    const int c = c0 + tcr, i = i0 + ti;
    if (c < NC && i < ND) {
        const float num = acc - (float)DE * ws[O_CMU + c] * ws[O_DMU + i];
        const float corr = num * ws[O_CIS + c] * ws[O_DIS + i];
        out[c * ND + i] = 1.f / (1.f + expf(-GAMMA_C * corr));
    }
}

static inline void jclear(Job& j) {
    for (int z = 0; z < 16; ++z) {
        j.aoff[z] = j.boff[z] = j.lda[z] = j.ldb[z] = 0;
        j.len[z] = j.blim[z] = j.coff[z] = j.bflag[z] = 0;
        j.rsg[z] = 1.f;
    }
}

extern "C" void kernel_launch(void* const* d_in, const int* in_sizes, int n_in,
                              void* d_out, int out_size, void* d_ws, size_t ws_size,
                              hipStream_t stream)
{
    const float* adj         = (const float*)d_in[0];
    const float* cell_exprs  = (const float*)d_in[1];
    const float* drug_finger = (const float*)d_in[2];
    const float* cell_hyper  = (const float*)d_in[3];
    const float* drug_hyper  = (const float*)d_in[4];
    const float* W_agg       = (const float*)d_in[5];
    const float* b_agg       = (const float*)d_in[6];
    const float* ldd_w       = (const float*)d_in[7];
    const float* lcc_w       = (const float*)d_in[9];
    const float* bnd_g       = (const float*)d_in[11];
    const float* bnd_b       = (const float*)d_in[12];
    const float* bnc_g       = (const float*)d_in[13];
    const float* bnc_b       = (const float*)d_in[14];
    float* ws  = (float*)d_ws;
    float* out = (float*)d_out;
    f16* h16 = (f16*)(ws + O_H16);

    // 1) scalars
    k_pre<<<NC + ND, 256, 0, stream>>>(adj, cell_hyper, drug_hyper, ws);
    // 2) z-norm stats
    k_zstats<<<NC, 256, 0, stream>>>(cell_exprs, ws);
    // 3) fp16 operand pool (scale-folded, padded)
    k_cvt<<<2048, 256, 0, stream>>>(cell_exprs, drug_finger, ldd_w, adj,
                                    cell_hyper, drug_hyper, ws, h16);

    // 4) exp = cx16 @ lcc_w^T (K 17760 padded, 10 windows of 1776) -> slabs
    {
        Job j; jclear(j);
        for (int z = 0; z < 10; ++z) {
            j.aoff[z] = H_CX + z * 1776; j.lda[z] = 17760;
            j.boff[z] = z * 1776;        j.ldb[z] = NG;
            j.len[z] = 1776;
            int bl = NG - z * 1776; j.blim[z] = bl > 1776 ? 1776 : bl;
            j.coff[z] = O_PS + z * (NC * DE);
        }
        k_fgemm<64, 128, 2, 0><<<dim3(16, 1, 10), 256, 0, stream>>>(
            h16, lcc_w, ws, h16, nullptr, 0, NC, DE, DE, 10, 1, j);
        k_reduce<<<479, 256, 0, stream>>>(ws + O_PS, ws + O_EMBC, 10, NC * DE, NC * DE);
    }
    // 5) fig = df16 @ ldw16^T (K=896) -> embD direct
    {
        Job j; jclear(j);
        j.aoff[0] = H_DF; j.lda[0] = 896;
        j.boff[0] = H_LDW; j.ldb[0] = 896;
        j.len[0] = 896; j.coff[0] = O_EMBD;
        k_fgemm<64, 128, 0, 0><<<dim3(16, 15, 1), 256, 0, stream>>>(
            h16, h16, ws, h16, nullptr, 0, ND, DE, DE, 1, 0, j);
    }
    // 6) BN (in-place fp32) + expT16/figT16
    k_bn<<<16, 256, 0, stream>>>(ws, h16, bnc_g, bnc_b, bnd_g, bnd_b);
    // 7) Xc/Xd block0
    k_buildX<<<8065, 256, 0, stream>>>(ws, h16);

    // 8) cell X-jobs: X1 / X4 / X6 in one launch
    {
        Job j; jclear(j);
        j.aoff[0] = H_ALC; j.lda[0] = 960; j.boff[0] = H_FIGT; j.ldb[0] = 960;
        j.len[0] = 960; j.coff[0] = H_XC + DE;
        j.aoff[1] = H_CH; j.lda[1] = 64; j.boff[1] = H_EXPT; j.ldb[1] = 64;
        j.len[1] = 64; j.coff[1] = H_XC + 2 * DE;
        j.aoff[2] = H_CHS; j.lda[2] = 64; j.boff[2] = H_EXPT; j.ldb[2] = 64;
        j.len[2] = 64; j.coff[2] = H_XC + 3 * DE; j.rsg[2] = -1.f; j.bflag[2] = 1;
        k_fgemm<64, 128, 0, 1><<<dim3(16, 1, 3), 256, 0, stream>>>(
            h16, h16, ws, h16, ws + O_EMBC, DE, NC, DE, 4 * DE, 3, 1, j);
    }
    // 9) drug X-jobs: X3 / X5 / X7 in one launch
    {
        Job j; jclear(j);
        j.aoff[0] = H_ALD; j.lda[0] = 64; j.boff[0] = H_EXPT; j.ldb[0] = 64;
        j.len[0] = 64; j.coff[0] = H_XD + DE;
        j.aoff[1] = H_DH; j.lda[1] = 960; j.boff[1] = H_FIGT; j.ldb[1] = 960;
        j.len[1] = 960; j.coff[1] = H_XD + 2 * DE;
        j.aoff[2] = H_DHS; j.lda[2] = 960; j.boff[2] = H_FIGT; j.ldb[2] = 960;
        j.len[2] = 960; j.coff[2] = H_XD + 3 * DE; j.rsg[2] = -1.f; j.bflag[2] = 1;
        k_fgemm<128, 128, 0, 1><<<dim3(16, 8, 3), 256, 0, stream>>>(
            h16, h16, ws, h16, ws + O_EMBD, DE, ND, DE, 4 * DE, 3, 1, j);
    }
    // 10) cell main: Xc16 @ [W0|W1|W4|W6]^T (8 windows) -> slabs -> csum
    {
        const int permc[4] = {0, 1, 4, 6};
        Job j; jclear(j);
        for (int z = 0; z < 8; ++z) {
            const int ib = z >> 1, sub = z & 1;
            j.aoff[z] = H_XC + ib * DE + sub * 1024; j.lda[z] = 4 * DE;
            j.boff[z] = permc[ib] * DE * DE + sub * 1024; j.ldb[z] = DE;
            j.len[z] = sub ? 1016 : 1024;
            j.coff[z] = O_PS + z * (NC * DE);
        }
        k_fgemm<64, 128, 1, 0><<<dim3(16, 1, 8), 256, 0, stream>>>(
            h16, W_agg, ws, h16, nullptr, 0, NC, DE, DE, 8, 1, j);
        k_reduce<<<479, 256, 0, stream>>>(ws + O_PS, ws + O_CSUM, 8, NC * DE, NC * DE);
    }
    // 11) drug main: Xd16 @ [W2|W3|W5|W7]^T (4 windows in-loop) -> dsum
    {
        const int permd[4] = {2, 3, 5, 7};
        Job j; jclear(j);
        for (int z = 0; z < 4; ++z) {
            j.aoff[z] = H_XD + z * DE; j.lda[z] = 4 * DE;
            j.boff[z] = permd[z] * DE * DE; j.ldb[z] = DE;
            j.len[z] = DE;
        }
        j.coff[0] = O_DSUM;
        k_fgemm<128, 64, 1, 0><<<dim3(32, 8, 1), 256, 0, stream>>>(
            h16, W_agg, ws, h16, nullptr, 0, ND, DE, DE, 4, 0, j);
    }

    // 12) epilogue, stats, corr
    k_epi<<<8065, 256, 0, stream>>>(ws, b_agg);
    k_rowstats<<<NC + ND, 256, 0, stream>>>(ws);
    k_corr<<<dim3(60, 4), 256, 0, stream>>>(ws, out);

    (void)in_sizes; (void)n_in; (void)out_size; (void)ws_size;
}